// Round 6
// baseline (206.061 us; speedup 1.0000x reference)
//
#include <hip/hip_runtime.h>
#include <hip/hip_cooperative_groups.h>
#include <stdint.h>

namespace cg = cooperative_groups;

#define N 4096
#define GD 64                  // 64x64 cells of 8 px over 512x512 (r=5<8 => 3x3 walk)
#define CAP 16                 // bucket capacity (Poisson(1): overflow ~1e-15)
#define ECAP 6144              // directed edges per class (expect ~1500)
#define EBUF 1024              // per-block LDS edge staging (expect ~125/class)

// monotonic float32 -> uint32 mapping (order-preserving)
__device__ __forceinline__ uint32_t f2s(float f) {
    uint32_t u = __float_as_uint(f);
    return (u & 0x80000000u) ? ~u : (u | 0x80000000u);
}

__global__ void __launch_bounds__(256, 1)
k_all(const float* __restrict__ logits, const float* __restrict__ boxes,
      const float* __restrict__ tsz, float* __restrict__ out,
      float2* __restrict__ pts, uint64_t* __restrict__ keys,
      float* __restrict__ scores, uint32_t* __restrict__ ranks,
      uint32_t* __restrict__ cellcnt, uint16_t* __restrict__ buckets,
      uint32_t* __restrict__ edges, uint32_t* __restrict__ ecnt)
{
    cg::grid_group grid = cg::this_grid();
    __shared__ __align__(16) char smem[53248];     // phase-aliased LDS
    __shared__ int scount[2], sbase[2], schanged;
    const int tid = threadIdx.x, bid = blockIdx.x;

    // ---- Phase A: prep (blocks 0..15); zero counters (blocks 16..31) ----
    float px = 0.f, py = 0.f;
    uint64_t ki0 = 0, ki1 = 0;
    int cx = 0, cy = 0;
    bool vi0 = false, vi1 = false;
    if (bid < 16) {
        int i = bid * 256 + tid;
        float w = tsz[0], h = tsz[1];
        float x0 = logits[i*3+0], x1 = logits[i*3+1], x2 = logits[i*3+2];
        float mx = fmaxf(x0, fmaxf(x1, x2));
        float e0 = expf(x0 - mx), e1 = expf(x1 - mx), e2 = expf(x2 - mx);
        float sum = e0 + e1 + e2;
        px = boxes[i*2+0] * w; py = boxes[i*2+1] * h;
        out[i*5+0] = 1.0f - e2 / sum;      // tgt score
        out[i*5+1] = px;                   // x (exact)
        out[i*5+2] = py;                   // y (exact)
        pts[i] = make_float2(px, py);
        float s0 = e0 / sum, s1 = e1 / sum;
        scores[i]     = s0;
        scores[N + i] = s1;
        vi0 = (s0 >= 0.05f); vi1 = (s1 >= 0.05f);
        uint32_t k0 = vi0 ? f2s(s0) : 0u;  // invalid sorts last
        uint32_t k1 = vi1 ? f2s(s1) : 0u;
        // tie-break: smaller original index first under DESCENDING sort
        ki0 = ((uint64_t)k0 << 32) | (uint32_t)(~(uint32_t)i);
        ki1 = ((uint64_t)k1 << 32) | (uint32_t)(~(uint32_t)i);
        keys[i]     = ki0;
        keys[N + i] = ki1;
        cx = min(max((int)(px * 0.125f), 0), GD - 1);
        cy = min(max((int)(py * 0.125f), 0), GD - 1);
    } else if (bid < 32) {
        int z = (bid - 16) * 256 + tid;    // 0..4095
        cellcnt[z] = 0;
        if (z < 2) ecnt[z] = 0;
    }
    grid.sync();

    // ---- Phase B: spatial binning (blocks 0..15, from registers) ----
    if (bid < 16) {
        int i = bid * 256 + tid;
        int c = cy * GD + cx;
        uint32_t pos = atomicAdd(&cellcnt[c], 1u);
        if (pos < CAP) buckets[c*CAP + pos] = (uint16_t)i;
    }
    grid.sync();

    // ---- Phase C: rank-by-count (all 256 blocks) ----
    {
        uint64_t* sk = (uint64_t*)smem;                        // 32 KB
        uint32_t (*part)[8] = (uint32_t(*)[8])(smem + 32768);  // 1 KB
        int cls = bid >> 7, seg = bid & 127;
        const uint64_t* kc = keys + cls * N;
        for (int r = tid; r < N; r += 256) sk[r] = kc[r];
        __syncthreads();
        int pl  = tid & 31;                // point within 32-segment
        int sub = tid >> 5;                // 0..7 subranges of 512
        uint64_t my = sk[seg*32 + pl];
        int cnt = 0, j0 = sub * (N/8);
        #pragma unroll 4
        for (int j = j0; j < j0 + N/8; ++j) cnt += (sk[j] > my) ? 1 : 0;
        part[pl][sub] = (uint32_t)cnt;
        __syncthreads();
        if (tid < 32) {
            uint32_t r = 0;
            #pragma unroll
            for (int s = 0; s < 8; ++s) r += part[tid][s];
            ranks[cls*N + seg*32 + tid] = r;
        }
    }
    // ---- Phase C2: pair walk -> directed valid-valid edges (blocks 0..15) ----
    if (bid < 16) {
        __syncthreads();                   // sk/part reads done; realias
        uint32_t* sbuf0 = (uint32_t*)smem;
        uint32_t* sbuf1 = (uint32_t*)(smem + EBUF*4);
        if (tid < 2) scount[tid] = 0;
        __syncthreads();
        int i = bid * 256 + tid;
        if (vi0 || vi1) {
            for (int dy = -1; dy <= 1; ++dy) {
                int yy = cy + dy; if (yy < 0 || yy >= GD) continue;
                for (int dx = -1; dx <= 1; ++dx) {
                    int xx = cx + dx; if (xx < 0 || xx >= GD) continue;
                    int c = yy * GD + xx;
                    int n = min((int)cellcnt[c], CAP);
                    for (int t = 0; t < n; ++t) {
                        int j = buckets[c*CAP + t];
                        if (j <= i) continue;          // each unordered pair once
                        float2 q = pts[j];
                        float ddx = __fsub_rn(px, q.x);
                        float ddy = __fsub_rn(py, q.y);
                        float d2 = __fadd_rn(__fmul_rn(ddx, ddx), __fmul_rn(ddy, ddy));
                        if (d2 >= 25.0f) continue;
                        uint64_t kj0 = keys[j], kj1 = keys[N + j];
                        if (vi0 && (uint32_t)(kj0 >> 32) != 0u) {
                            int u = (ki0 > kj0) ? i : j;   // bigger key = earlier
                            int v = i + j - u;
                            int pos = atomicAdd(&scount[0], 1);
                            if (pos < EBUF) sbuf0[pos] = ((uint32_t)u << 12) | (uint32_t)v;
                        }
                        if (vi1 && (uint32_t)(kj1 >> 32) != 0u) {
                            int u = (ki1 > kj1) ? i : j;
                            int v = i + j - u;
                            int pos = atomicAdd(&scount[1], 1);
                            if (pos < EBUF) sbuf1[pos] = ((uint32_t)u << 12) | (uint32_t)v;
                        }
                    }
                }
            }
        }
        __syncthreads();
        if (tid < 2) {
            int c = min(scount[tid], EBUF);
            sbase[tid] = (int)atomicAdd(&ecnt[tid], (uint32_t)c);
            scount[tid] = c;
        }
        __syncthreads();
        for (int k = tid; k < scount[0]; k += 256) {
            int p = sbase[0] + k; if (p < ECAP) edges[p] = sbuf0[k];
        }
        for (int k = tid; k < scount[1]; k += 256) {
            int p = sbase[1] + k; if (p < ECAP) edges[ECAP + p] = sbuf1[k];
        }
    }
    grid.sync();

    // ---- Phase D: Jacobi fixpoint + scatter (blocks 0,1; others exit) ----
    // keep[v] = valid[v] & !any(u->v edge with keep[u]); unique fixpoint on
    // the key-ordered DAG == greedy NMS; converges in <= chain-depth rounds.
    if (bid >= 2) return;
    {
        const int cls = bid;
        float*    ssc    = (float*)smem;                  // 16 KB
        uint16_t* r16    = (uint16_t*)(smem + 16384);     //  8 KB
        uint32_t* sedge  = (uint32_t*)(smem + 24576);     // 24 KB
        uint32_t* validw = (uint32_t*)(smem + 49152);     // 512 B
        uint32_t* keepw  = validw + 128;
        uint32_t* suppw  = validw + 256;
        __syncthreads();                                  // realias safety
        int ec = min((int)ecnt[cls], ECAP);
        for (int k = tid; k < N; k += 256) {
            ssc[k] = scores[cls*N + k];
            r16[k] = (uint16_t)ranks[cls*N + k];
        }
        for (int k = tid; k < ec; k += 256) sedge[k] = edges[cls*ECAP + k];
        __syncthreads();
        if (tid < 128) {
            uint32_t wb = 0;
            #pragma unroll
            for (int b = 0; b < 32; ++b)
                if (ssc[tid*32 + b] >= 0.05f) wb |= 1u << b;
            validw[tid] = wb; keepw[tid] = wb;
        }
        __syncthreads();
        for (int round = 0; round < N; ++round) {
            if (tid < 128) suppw[tid] = 0;
            if (tid == 0) schanged = 0;
            __syncthreads();
            for (int k = tid; k < ec; k += 256) {
                uint32_t e = sedge[k];
                int u = e >> 12, v = e & (N - 1);
                if ((keepw[u >> 5] >> (u & 31)) & 1u)
                    atomicOr(&suppw[v >> 5], 1u << (v & 31));
            }
            __syncthreads();
            if (tid < 128) {
                uint32_t nw = validw[tid] & ~suppw[tid];
                if (nw != keepw[tid]) { keepw[tid] = nw; schanged = 1; }
            }
            __syncthreads();
            if (!schanged) break;
        }
        // output per SORTED slot (ranks form a permutation of 0..N-1)
        for (int k = tid; k < N; k += 256) {
            int slot = r16[k];
            bool kp = (keepw[k >> 5] >> (k & 31)) & 1u;
            out[slot*5 + 3 + cls] = kp ? ssc[k] : 0.0f;
        }
    }
}

extern "C" void kernel_launch(void* const* d_in, const int* in_sizes, int n_in,
                              void* d_out, int out_size, void* d_ws, size_t ws_size,
                              hipStream_t stream) {
    const float* logits = (const float*)d_in[0];  // [1,4096,3]
    const float* boxes  = (const float*)d_in[1];  // [1,4096,2]
    // d_in[2] = pred_gids, unused by the reference
    const float* tsz    = (const float*)d_in[3];  // [1,2]
    float* out = (float*)d_out;                   // [1,4096,5]

    uint8_t* ws = (uint8_t*)d_ws;
    uint32_t* ecnts   = (uint32_t*)ws;                        // @0, 2 counters
    uint32_t* cellcnt = (uint32_t*)(ws + 256);                // 16 KB
    uint16_t* buckets = (uint16_t*)(ws + 16640);              // 128 KB
    float2*   pts     = (float2*)  (ws + 147712);             // 32 KB
    uint64_t* keys    = (uint64_t*)(ws + 180480);             // 64 KB (2 cls)
    uint32_t* ranks   = (uint32_t*)(ws + 246016);             // 32 KB
    float*    scores  = (float*)   (ws + 278784);             // 32 KB
    uint32_t* edges   = (uint32_t*)(ws + 311552);             // 48 KB (2 x ECAP)

    void* args[] = { (void*)&logits, (void*)&boxes, (void*)&tsz, (void*)&out,
                     (void*)&pts, (void*)&keys, (void*)&scores, (void*)&ranks,
                     (void*)&cellcnt, (void*)&buckets, (void*)&edges, (void*)&ecnts };
    hipLaunchCooperativeKernel((void*)k_all, dim3(256), dim3(256), args, 0, stream);
}

// Round 8
// 149.297 us; speedup vs baseline: 1.3802x; 1.3802x over previous
//
#include <hip/hip_runtime.h>
#include <stdint.h>

#define N 4096
#define GD 64                  // 64x64 cells of 8 px over 512x512 (r=5<8 => 3x3 walk)
#define CAP 16                 // bucket capacity (Poisson(1): overflow ~1e-15)
#define EBUFB 512              // per-chunk per-class edge region (expect ~125)
#define SECAP 8192             // staged edges cap in resolve
#define MAGIC 0xC0FFEE01u      // flag value (ws poison is 0xAAAAAAAA)

// monotonic float32 -> uint32 mapping (order-preserving)
__device__ __forceinline__ uint32_t f2s(float f) {
    uint32_t u = __float_as_uint(f);
    return (u & 0x80000000u) ? ~u : (u | 0x80000000u);
}

__device__ __forceinline__ void setflag(uint32_t* f) {
    __threadfence();   // agent-scope writeback of prior plain stores
    __hip_atomic_store(f, MAGIC, __ATOMIC_RELEASE, __HIP_MEMORY_SCOPE_AGENT);
}
__device__ __forceinline__ void waitflag(uint32_t* f) {
    for (int it = 0; it < 3000000; ++it) {   // bounded hang-guard (~0.4 s)
        if (__hip_atomic_load(f, __ATOMIC_ACQUIRE, __HIP_MEMORY_SCOPE_AGENT) == MAGIC)
            return;
        __builtin_amdgcn_s_sleep(1);
    }
}

__global__ void __launch_bounds__(256, 2)
k_all(const float* __restrict__ logits, const float* __restrict__ boxes,
      const float* __restrict__ tsz, float* __restrict__ out,
      uint32_t* __restrict__ flagZ, uint32_t* __restrict__ flagP,
      uint32_t* __restrict__ flagR, uint32_t* __restrict__ flagE,
      uint32_t* __restrict__ ecountG, uint32_t* __restrict__ cellcnt,
      uint16_t* __restrict__ buckets, float2* __restrict__ pts,
      uint64_t* __restrict__ keys, float* __restrict__ scores,
      uint32_t* __restrict__ ranks, uint32_t* __restrict__ edgesG)
{
    const int tid = threadIdx.x, bid = blockIdx.x;
    __shared__ __align__(16) char smem[57344];   // phase-aliased
    __shared__ uint32_t validw[128], keepw[128], suppw[128];
    __shared__ int scount[2], schanged;

    // ---- Phase A ----
    float px = 0.f, py = 0.f;
    int cx = 0, cy = 0;
    if (bid < 16) {
        // prep: softmax, direct outputs, pts/keys/scores (state kept in regs)
        int i = bid * 256 + tid;
        float w = tsz[0], h = tsz[1];
        float x0 = logits[i*3+0], x1 = logits[i*3+1], x2 = logits[i*3+2];
        float mx = fmaxf(x0, fmaxf(x1, x2));
        float e0 = expf(x0 - mx), e1 = expf(x1 - mx), e2 = expf(x2 - mx);
        float sum = e0 + e1 + e2;
        px = boxes[i*2+0] * w; py = boxes[i*2+1] * h;
        out[i*5+0] = 1.0f - e2 / sum;      // tgt score
        out[i*5+1] = px;                   // x (exact)
        out[i*5+2] = py;                   // y (exact)
        pts[i] = make_float2(px, py);
        float s0 = e0 / sum, s1 = e1 / sum;
        scores[i]     = s0;
        scores[N + i] = s1;
        uint32_t k0 = (s0 >= 0.05f) ? f2s(s0) : 0u;   // invalid sorts last
        uint32_t k1 = (s1 >= 0.05f) ? f2s(s1) : 0u;
        // tie-break: smaller original index first under DESCENDING sort
        keys[i]     = ((uint64_t)k0 << 32) | (uint32_t)(~(uint32_t)i);
        keys[N + i] = ((uint64_t)k1 << 32) | (uint32_t)(~(uint32_t)i);
        cx = min(max((int)(px * 0.125f), 0), GD - 1);
        cy = min(max((int)(py * 0.125f), 0), GD - 1);
    } else if (bid < 32) {
        // zero the cell counts (replaces the memset node)
        cellcnt[(bid - 16) * 256 + tid] = 0;
        __syncthreads();
        if (tid == 0) setflag(&flagZ[bid - 16]);
    }

    // ---- Phase B: binning (blocks 0..15) ----
    if (bid < 16) {
        if (tid < 16) waitflag(&flagZ[tid]);
        __syncthreads();
        int i = bid * 256 + tid;
        int c = cy * GD + cx;
        uint32_t pos = atomicAdd(&cellcnt[c], 1u);
        if (pos < CAP) buckets[c*CAP + pos] = (uint16_t)i;
        __syncthreads();
        if (tid == 0) setflag(&flagP[bid]);
    }

    // ---- Phase C: rank-by-count (all 256 blocks) ----
    if (tid < 16) waitflag(&flagP[tid]);
    __syncthreads();
    {
        uint64_t* sk = (uint64_t*)smem;                        // 32 KB
        uint32_t (*part)[8] = (uint32_t(*)[8])(smem + 32768);  // 1 KB
        int cls = bid >> 7, seg = bid & 127;
        const uint64_t* kc = keys + cls * N;
        for (int r = tid; r < N; r += 256) sk[r] = kc[r];
        __syncthreads();
        int pl  = tid & 31;                // point within 32-segment
        int sub = tid >> 5;                // 0..7 subranges of 512
        uint64_t my = sk[seg*32 + pl];
        int cnt = 0, j0 = sub * (N/8);
        #pragma unroll 4
        for (int j = j0; j < j0 + N/8; ++j) cnt += (sk[j] > my) ? 1 : 0;
        part[pl][sub] = (uint32_t)cnt;
        __syncthreads();
        if (tid < 32) {
            uint32_t r = 0;
            #pragma unroll
            for (int s = 0; s < 8; ++s) r += part[tid][s];
            ranks[cls*N + seg*32 + tid] = r;
        }
        __syncthreads();
        if (tid == 0) setflag(&flagR[bid]);
    }

    // ---- Phase C2: pair walk -> directed edges (blocks 16..31) ----
    if (bid >= 16 && bid < 32) {
        __syncthreads();                   // realias smem
        uint32_t* sbuf0 = (uint32_t*)smem;
        uint32_t* sbuf1 = (uint32_t*)(smem + EBUFB*4);
        if (tid < 2) scount[tid] = 0;
        __syncthreads();
        int chunk = bid - 16;
        int i = chunk * 256 + tid;
        float2 p = pts[i];
        uint64_t ki0 = keys[i], ki1 = keys[N + i];
        bool vi0 = (uint32_t)(ki0 >> 32) != 0u;
        bool vi1 = (uint32_t)(ki1 >> 32) != 0u;
        int pcx = min(max((int)(p.x * 0.125f), 0), GD - 1);
        int pcy = min(max((int)(p.y * 0.125f), 0), GD - 1);
        if (vi0 || vi1) {
            for (int dy = -1; dy <= 1; ++dy) {
                int yy = pcy + dy; if (yy < 0 || yy >= GD) continue;
                for (int dx = -1; dx <= 1; ++dx) {
                    int xx = pcx + dx; if (xx < 0 || xx >= GD) continue;
                    int c = yy * GD + xx;
                    int n = min((int)cellcnt[c], CAP);
                    for (int t = 0; t < n; ++t) {
                        int j = buckets[c*CAP + t];
                        if (j <= i) continue;          // each unordered pair once
                        float2 q = pts[j];
                        float ddx = __fsub_rn(p.x, q.x);
                        float ddy = __fsub_rn(p.y, q.y);
                        float d2 = __fadd_rn(__fmul_rn(ddx, ddx), __fmul_rn(ddy, ddy));
                        if (d2 >= 25.0f) continue;
                        uint64_t kj0 = keys[j], kj1 = keys[N + j];
                        if (vi0 && (uint32_t)(kj0 >> 32) != 0u) {
                            int u = (ki0 > kj0) ? i : j;   // bigger key = earlier
                            int v = i + j - u;
                            int pos = atomicAdd(&scount[0], 1);
                            if (pos < EBUFB) sbuf0[pos] = ((uint32_t)u << 12) | (uint32_t)v;
                        }
                        if (vi1 && (uint32_t)(kj1 >> 32) != 0u) {
                            int u = (ki1 > kj1) ? i : j;
                            int v = i + j - u;
                            int pos = atomicAdd(&scount[1], 1);
                            if (pos < EBUFB) sbuf1[pos] = ((uint32_t)u << 12) | (uint32_t)v;
                        }
                    }
                }
            }
        }
        __syncthreads();
        int c0 = min(scount[0], EBUFB), c1 = min(scount[1], EBUFB);
        for (int k = tid; k < c0; k += 256) edgesG[chunk*EBUFB + k]             = sbuf0[k];
        for (int k = tid; k < c1; k += 256) edgesG[(16 + chunk)*EBUFB + k]      = sbuf1[k];
        if (tid == 0) { ecountG[chunk] = (uint32_t)c0; ecountG[16 + chunk] = (uint32_t)c1; }
        __syncthreads();
        if (tid == 0) setflag(&flagE[chunk]);
    }

    if (bid >= 2) return;

    // ---- Phase D: Jacobi fixpoint + scatter (blocks 0,1) ----
    // keep[v] = valid[v] & !any(u->v edge with keep[u]); unique fixpoint on
    // the key-ordered DAG == greedy NMS; converges in <= chain-depth rounds.
    {
        const int cls = bid;
        waitflag(&flagR[tid]);             // one rank flag per thread (256)
        if (tid < 16) waitflag(&flagE[tid]);
        __syncthreads();                   // also fences smem realias

        float*    ssc   = (float*)smem;                  // 16 KB
        uint16_t* r16   = (uint16_t*)(smem + 16384);     //  8 KB
        uint32_t* sedge = (uint32_t*)(smem + 24576);     // 32 KB
        for (int k = tid; k < N; k += 256) {
            ssc[k] = scores[cls*N + k];
            r16[k] = (uint16_t)ranks[cls*N + k];
        }
        int pref[16], cnts[16], total = 0;
        #pragma unroll
        for (int b = 0; b < 16; ++b) {
            pref[b] = total;
            int c = min((int)ecountG[cls*16 + b], EBUFB);
            cnts[b] = c; total += c;
        }
        int ec = min(total, SECAP);
        #pragma unroll
        for (int b = 0; b < 16; ++b) {
            for (int k = tid; k < cnts[b]; k += 256) {
                int d = pref[b] + k;
                if (d < SECAP) sedge[d] = edgesG[(cls*16 + b)*EBUFB + k];
            }
        }
        __syncthreads();
        if (tid < 128) {
            uint32_t wb = 0;
            #pragma unroll
            for (int b = 0; b < 32; ++b)
                if (ssc[tid*32 + b] >= 0.05f) wb |= 1u << b;
            validw[tid] = wb; keepw[tid] = wb;
        }
        __syncthreads();
        for (int round = 0; round < N; ++round) {
            if (tid < 128) suppw[tid] = 0;
            if (tid == 0) schanged = 0;
            __syncthreads();
            for (int k = tid; k < ec; k += 256) {
                uint32_t e = sedge[k];
                int u = e >> 12, v = e & (N - 1);
                if ((keepw[u >> 5] >> (u & 31)) & 1u)
                    atomicOr(&suppw[v >> 5], 1u << (v & 31));
            }
            __syncthreads();
            if (tid < 128) {
                uint32_t nw = validw[tid] & ~suppw[tid];
                if (nw != keepw[tid]) { keepw[tid] = nw; schanged = 1; }
            }
            __syncthreads();
            if (!schanged) break;
        }
        // output per SORTED slot (ranks form a permutation of 0..N-1)
        for (int k = tid; k < N; k += 256) {
            int slot = r16[k];
            bool kp = (keepw[k >> 5] >> (k & 31)) & 1u;
            out[slot*5 + 3 + cls] = kp ? ssc[k] : 0.0f;
        }
    }
}

extern "C" void kernel_launch(void* const* d_in, const int* in_sizes, int n_in,
                              void* d_out, int out_size, void* d_ws, size_t ws_size,
                              hipStream_t stream) {
    const float* logits = (const float*)d_in[0];  // [1,4096,3]
    const float* boxes  = (const float*)d_in[1];  // [1,4096,2]
    // d_in[2] = pred_gids, unused by the reference
    const float* tsz    = (const float*)d_in[3];  // [1,2]
    float* out = (float*)d_out;                   // [1,4096,5]

    uint8_t* ws = (uint8_t*)d_ws;
    uint32_t* flagZ   = (uint32_t*)(ws + 0);        // 16
    uint32_t* flagP   = (uint32_t*)(ws + 64);       // 16
    uint32_t* flagR   = (uint32_t*)(ws + 128);      // 256
    uint32_t* flagE   = (uint32_t*)(ws + 1152);     // 16
    uint32_t* ecountG = (uint32_t*)(ws + 1216);     // 32
    uint32_t* cellcnt = (uint32_t*)(ws + 2048);     // 16 KB
    uint16_t* buckets = (uint16_t*)(ws + 18432);    // 128 KB
    float2*   pts     = (float2*)  (ws + 149504);   // 32 KB
    uint64_t* keys    = (uint64_t*)(ws + 182272);   // 64 KB (2 classes)
    uint32_t* ranks   = (uint32_t*)(ws + 247808);   // 32 KB
    float*    scores  = (float*)   (ws + 280576);   // 32 KB
    uint32_t* edgesG  = (uint32_t*)(ws + 313344);   // 64 KB (32 x EBUFB)

    hipLaunchKernelGGL(k_all, dim3(256), dim3(256), 0, stream,
                       logits, boxes, tsz, out,
                       flagZ, flagP, flagR, flagE, ecountG,
                       cellcnt, buckets, pts, keys, scores, ranks, edgesG);
}

// Round 9
// 112.424 us; speedup vs baseline: 1.8329x; 1.3280x over previous
//
#include <hip/hip_runtime.h>
#include <stdint.h>

#define N 4096
#define RG 32                 // 32x32 cells of 16 px over 512x512
#define CAP 24                // bucket capacity (Binom(4096,1/1024) tail ~1e-12)
#define ECAP 6144             // directed edges per class (expect ~1500)

// monotonic float32 -> uint32 mapping (order-preserving)
__device__ __forceinline__ uint32_t f2s(float f) {
    uint32_t u = __float_as_uint(f);
    return (u & 0x80000000u) ? ~u : (u | 0x80000000u);
}

// ---- K1: self-sufficient rank-by-count ----
// Each block recomputes ALL 4096 keys from logits (cheap), then ranks its
// 32-point segment: slot = #keys strictly greater (desc sort, stable by idx).
__global__ void __launch_bounds__(256)
k_rank(const float* __restrict__ logits, uint32_t* __restrict__ ranks)
{
    __shared__ uint64_t sk[N];             // 32 KB
    __shared__ uint32_t part[32][8];
    const int tid = threadIdx.x, bid = blockIdx.x;
    const int cls = bid >> 7, seg = bid & 127;
    for (int r = 0; r < 16; ++r) {
        int i = r * 256 + tid;
        float x0 = logits[i*3+0], x1 = logits[i*3+1], x2 = logits[i*3+2];
        float mx = fmaxf(x0, fmaxf(x1, x2));
        float e0 = expf(x0 - mx), e1 = expf(x1 - mx), e2 = expf(x2 - mx);
        float s = (cls ? e1 : e0) / (e0 + e1 + e2);
        uint32_t kk = (s >= 0.05f) ? f2s(s) : 0u;   // invalid sorts last
        // tie-break: smaller original index first under DESCENDING sort
        sk[i] = ((uint64_t)kk << 32) | (uint32_t)(~(uint32_t)i);
    }
    __syncthreads();
    int pl = tid & 31, sub = tid >> 5;     // 8 threads/point x 512 compares
    uint64_t my = sk[seg*32 + pl];
    int cnt = 0, j0 = sub * (N/8);
    #pragma unroll 4
    for (int j = j0; j < j0 + N/8; ++j) cnt += (sk[j] > my) ? 1 : 0;
    part[pl][sub] = (uint32_t)cnt;
    __syncthreads();
    if (tid < 32) {
        uint32_t r = 0;
        #pragma unroll
        for (int s = 0; s < 8; ++s) r += part[tid][s];
        ranks[cls*N + seg*32 + tid] = r;
    }
}

// ---- K2: per-class all-LDS pipeline: prep -> bin -> walk -> Jacobi -> scatter ----
// keep[v] = valid[v] & !any(u->v edge with keep[u]); unique fixpoint on the
// key-ordered DAG == greedy NMS; converges in <= chain-depth rounds.
__global__ void __launch_bounds__(1024, 1)
k_resolve(const float* __restrict__ logits, const float* __restrict__ boxes,
          const float* __restrict__ tsz, const uint32_t* __restrict__ ranks,
          float* __restrict__ out)
{
    __shared__ float2   spts[N];            // 32 KB
    __shared__ float    ssc[N];             // 16 KB
    __shared__ uint16_t r16[N];             //  8 KB
    __shared__ uint16_t bkt[RG*RG*CAP];     // 48 KB
    __shared__ uint32_t cnt[RG*RG];         //  4 KB
    __shared__ uint32_t sedge[ECAP];        // 24 KB
    __shared__ uint32_t validw[128], keepw[128], suppw[128];
    __shared__ int ecnt, schanged;
    const int cls = blockIdx.x, tid = threadIdx.x;
    const float w = tsz[0], h = tsz[1];

    // prep: softmax, pixel pts, scores, direct outputs; ranks from K1
    for (int k = tid; k < N; k += 1024) {
        float x0 = logits[k*3+0], x1 = logits[k*3+1], x2 = logits[k*3+2];
        float mx = fmaxf(x0, fmaxf(x1, x2));
        float e0 = expf(x0 - mx), e1 = expf(x1 - mx), e2 = expf(x2 - mx);
        float sum = e0 + e1 + e2;
        float px = boxes[k*2+0] * w, py = boxes[k*2+1] * h;
        if (cls == 0) {
            out[k*5+0] = 1.0f - e2 / sum;  // tgt score
            out[k*5+1] = px;               // x (exact)
            out[k*5+2] = py;               // y (exact)
        }
        spts[k] = make_float2(px, py);
        ssc[k]  = (cls ? e1 : e0) / sum;
        r16[k]  = (uint16_t)ranks[cls*N + k];
    }
    if (tid < RG*RG) cnt[tid] = 0;          // RG*RG == 1024
    if (tid == 0) ecnt = 0;
    __syncthreads();

    // bin valid points into 16-px cells (LDS atomics)
    for (int k = tid; k < N; k += 1024) {
        if (ssc[k] < 0.05f) continue;
        float2 p = spts[k];
        int cx = min(max((int)(p.x * 0.0625f), 0), RG - 1);
        int cy = min(max((int)(p.y * 0.0625f), 0), RG - 1);
        uint32_t pos = atomicAdd(&cnt[cy*RG + cx], 1u);
        if (pos < CAP) bkt[(cy*RG + cx)*CAP + pos] = (uint16_t)k;
    }
    if (tid < 128) { validw[tid] = 0; }
    __syncthreads();

    // 2x2-cell pair walk: all j within 5 px of k lie in this window (5+5<16)
    for (int k = tid; k < N; k += 1024) {
        if (ssc[k] < 0.05f) continue;
        float2 p = spts[k];
        uint32_t sku = f2s(ssc[k]);
        int cx = min(max((int)(p.x * 0.0625f), 0), RG - 1);
        int cy = min(max((int)(p.y * 0.0625f), 0), RG - 1);
        float fx = p.x - 16.f * cx, fy = p.y - 16.f * cy;
        int xl = (fx < 5.f  && cx > 0     ) ? cx - 1 : cx;
        int xh = (fx > 11.f && cx < RG - 1) ? cx + 1 : cx;
        int yl = (fy < 5.f  && cy > 0     ) ? cy - 1 : cy;
        int yh = (fy > 11.f && cy < RG - 1) ? cy + 1 : cy;
        for (int yy = yl; yy <= yh; ++yy)
        for (int xx = xl; xx <= xh; ++xx) {
            int c = yy * RG + xx;
            int n = min((int)cnt[c], CAP);
            for (int t = 0; t < n; ++t) {
                int j = bkt[c*CAP + t];
                if (j <= k) continue;              // each unordered pair once
                float2 q = spts[j];
                float dx = __fsub_rn(p.x, q.x);
                float dy = __fsub_rn(p.y, q.y);
                float d2 = __fadd_rn(__fmul_rn(dx, dx), __fmul_rn(dy, dy));
                if (d2 >= 25.0f) continue;
                uint32_t sj = f2s(ssc[j]);
                // u earlier iff (score_u, -idx_u) > (score_v, -idx_v); j>k here
                int u = (sku >= sj) ? k : j;
                int v = k + j - u;
                int pos = atomicAdd(&ecnt, 1);
                if (pos < ECAP) sedge[pos] = ((uint32_t)u << 12) | (uint32_t)v;
            }
        }
    }
    __syncthreads();
    int ec = min(ecnt, ECAP);
    if (tid < 128) {
        uint32_t wb = 0;
        #pragma unroll
        for (int b = 0; b < 32; ++b)
            if (ssc[tid*32 + b] >= 0.05f) wb |= 1u << b;
        validw[tid] = wb; keepw[tid] = wb;
    }
    __syncthreads();

    // Jacobi fixpoint on LDS bitsets
    for (int round = 0; round < N; ++round) {
        if (tid < 128) suppw[tid] = 0;
        if (tid == 0) schanged = 0;
        __syncthreads();
        for (int e = tid; e < ec; e += 1024) {
            uint32_t ed = sedge[e];
            int u = ed >> 12, v = ed & (N - 1);
            if ((keepw[u >> 5] >> (u & 31)) & 1u)
                atomicOr(&suppw[v >> 5], 1u << (v & 31));
        }
        __syncthreads();
        if (tid < 128) {
            uint32_t nw = validw[tid] & ~suppw[tid];
            if (nw != keepw[tid]) { keepw[tid] = nw; schanged = 1; }
        }
        __syncthreads();
        if (!schanged) break;
    }

    // output per SORTED slot (ranks form a permutation of 0..N-1)
    for (int k = tid; k < N; k += 1024) {
        int slot = r16[k];
        bool kp = (keepw[k >> 5] >> (k & 31)) & 1u;
        out[slot*5 + 3 + cls] = kp ? ssc[k] : 0.0f;
    }
}

extern "C" void kernel_launch(void* const* d_in, const int* in_sizes, int n_in,
                              void* d_out, int out_size, void* d_ws, size_t ws_size,
                              hipStream_t stream) {
    const float* logits = (const float*)d_in[0];  // [1,4096,3]
    const float* boxes  = (const float*)d_in[1];  // [1,4096,2]
    // d_in[2] = pred_gids, unused by the reference
    const float* tsz    = (const float*)d_in[3];  // [1,2]
    float* out = (float*)d_out;                   // [1,4096,5]

    uint32_t* ranks = (uint32_t*)d_ws;            // 32 KB (2 classes)

    hipLaunchKernelGGL(k_rank,    dim3(256), dim3(256),  0, stream, logits, ranks);
    hipLaunchKernelGGL(k_resolve, dim3(2),   dim3(1024), 0, stream,
                       logits, boxes, tsz, ranks, out);
}

// Round 10
// 106.660 us; speedup vs baseline: 1.9320x; 1.0540x over previous
//
#include <hip/hip_runtime.h>
#include <stdint.h>

#define N 4096
#define RG 32                 // 32x32 cells of 16 px over 512x512
#define BCAP 20               // bucket cap; Poisson(4) tail @20 ~2e-10/cell
#define EBUFB 512             // per-chunk per-class edge region (expect ~150)
#define SECAP 8192            // staged edges cap in resolve (= 16*EBUFB)

// monotonic float32 -> uint32 mapping (order-preserving)
__device__ __forceinline__ uint32_t f2s(float f) {
    uint32_t u = __float_as_uint(f);
    return (u & 0x80000000u) ? ~u : (u | 0x80000000u);
}

// ---- K1: wide, self-sufficient. Roles by blockIdx:
//   all 256 : rank own 32-point segment (keys recomputed from logits)
//   0 / 128 : also stream per-class scores to ws
//   16..31  : also write out cols 0..2 for chunk (bid-16)
//   0..15   : also build directed edges for chunk bid (private LDS bins)
__global__ void __launch_bounds__(256, 1)
k_wide(const float* __restrict__ logits, const float* __restrict__ boxes,
       const float* __restrict__ tsz, float* __restrict__ out,
       float* __restrict__ sscG, uint32_t* __restrict__ ranks,
       uint32_t* __restrict__ edgesG, uint32_t* __restrict__ ecountG)
{
    __shared__ __align__(16) char smem[114688];
    __shared__ int scount[2];
    const int tid = threadIdx.x, bid = blockIdx.x;
    const int cls = bid >> 7, seg = bid & 127;

    // ---- rank phase (all blocks) ----
    {
        uint64_t* sk = (uint64_t*)smem;                         // 32 KB
        uint32_t (*part)[8] = (uint32_t(*)[8])(smem + 32768);   // 1 KB
        const bool wssc = (bid == 0 || bid == 128);
        for (int r = 0; r < 16; ++r) {
            int i = r * 256 + tid;
            float x0 = logits[i*3+0], x1 = logits[i*3+1], x2 = logits[i*3+2];
            float mx = fmaxf(x0, fmaxf(x1, x2));
            float e0 = expf(x0 - mx), e1 = expf(x1 - mx), e2 = expf(x2 - mx);
            float s = (cls ? e1 : e0) / (e0 + e1 + e2);
            if (wssc) sscG[cls*N + i] = s;
            uint32_t kk = (s >= 0.05f) ? f2s(s) : 0u;   // invalid sorts last
            // tie-break: smaller original index first under DESCENDING sort
            sk[i] = ((uint64_t)kk << 32) | (uint32_t)(~(uint32_t)i);
        }
        __syncthreads();
        int pl = tid & 31, sub = tid >> 5;     // 8 threads/point x 512 cmps
        uint64_t my = sk[seg*32 + pl];
        int cnt = 0, j0 = sub * (N/8);
        #pragma unroll 4
        for (int j = j0; j < j0 + N/8; j += 2) {
            ulong2 two = *(const ulong2*)&sk[j];   // 16B LDS read
            cnt += (two.x > my) ? 1 : 0;
            cnt += (two.y > my) ? 1 : 0;
        }
        part[pl][sub] = (uint32_t)cnt;
        __syncthreads();
        if (tid < 32) {
            uint32_t r = 0;
            #pragma unroll
            for (int s = 0; s < 8; ++s) r += part[tid][s];
            ranks[cls*N + seg*32 + tid] = r;
        }
    }

    // ---- out cols 0..2 (blocks 16..31) ----
    if (bid >= 16 && bid < 32) {
        int i = (bid - 16) * 256 + tid;
        float w = tsz[0], h = tsz[1];
        float x0 = logits[i*3+0], x1 = logits[i*3+1], x2 = logits[i*3+2];
        float mx = fmaxf(x0, fmaxf(x1, x2));
        float e0 = expf(x0 - mx), e1 = expf(x1 - mx), e2 = expf(x2 - mx);
        float sum = e0 + e1 + e2;
        out[i*5+0] = 1.0f - e2 / sum;          // tgt score
        out[i*5+1] = boxes[i*2+0] * w;         // x (exact)
        out[i*5+2] = boxes[i*2+1] * h;         // y (exact)
    }

    if (bid >= 16) return;

    // ---- edge phase (blocks 0..15): private bins + 2x2 walk ----
    __syncthreads();                           // rank-phase LDS reads done
    float2*   spts = (float2*)smem;                    // 32 KB @0
    uint32_t* sku0 = (uint32_t*)(smem + 32768);        // 16 KB
    uint32_t* sku1 = (uint32_t*)(smem + 49152);        // 16 KB
    uint32_t* cnt  = (uint32_t*)(smem + 65536);        //  4 KB
    uint16_t* bkt  = (uint16_t*)(smem + 69632);        // 40 KB
    uint32_t* sbuf0 = (uint32_t*)(smem + 110592);      //  2 KB
    uint32_t* sbuf1 = (uint32_t*)(smem + 112640);      //  2 KB

    for (int c = tid; c < RG*RG; c += 256) cnt[c] = 0;
    if (tid < 2) scount[tid] = 0;
    __syncthreads();
    {
        const float w = tsz[0], h = tsz[1];
        for (int k = tid; k < N; k += 256) {
            float x0 = logits[k*3+0], x1 = logits[k*3+1], x2 = logits[k*3+2];
            float mx = fmaxf(x0, fmaxf(x1, x2));
            float e0 = expf(x0 - mx), e1 = expf(x1 - mx), e2 = expf(x2 - mx);
            float sum = e0 + e1 + e2;
            float s0 = e0 / sum, s1 = e1 / sum;
            float px = boxes[k*2+0] * w, py = boxes[k*2+1] * h;
            spts[k] = make_float2(px, py);
            sku0[k] = (s0 >= 0.05f) ? f2s(s0) : 0u;
            sku1[k] = (s1 >= 0.05f) ? f2s(s1) : 0u;
            int cx = min(max((int)(px * 0.0625f), 0), RG - 1);
            int cy = min(max((int)(py * 0.0625f), 0), RG - 1);
            uint32_t pos = atomicAdd(&cnt[cy*RG + cx], 1u);
            if (pos < BCAP) bkt[(cy*RG + cx)*BCAP + pos] = (uint16_t)k;
        }
    }
    __syncthreads();
    {
        int i = bid * 256 + tid;               // this block's chunk, 1 pt/thread
        uint32_t k0 = sku0[i], k1 = sku1[i];
        if (k0 | k1) {
            float2 p = spts[i];
            int cx = min(max((int)(p.x * 0.0625f), 0), RG - 1);
            int cy = min(max((int)(p.y * 0.0625f), 0), RG - 1);
            float fx = p.x - 16.f * cx, fy = p.y - 16.f * cy;
            int xl = (fx < 5.f  && cx > 0     ) ? cx - 1 : cx;
            int xh = (fx > 11.f && cx < RG - 1) ? cx + 1 : cx;
            int yl = (fy < 5.f  && cy > 0     ) ? cy - 1 : cy;
            int yh = (fy > 11.f && cy < RG - 1) ? cy + 1 : cy;
            for (int yy = yl; yy <= yh; ++yy)
            for (int xx = xl; xx <= xh; ++xx) {
                int c = yy * RG + xx;
                int n = min((int)cnt[c], BCAP);
                for (int t = 0; t < n; ++t) {
                    int j = bkt[c*BCAP + t];
                    if (j <= i) continue;              // each unordered pair once
                    float2 q = spts[j];
                    float dx = __fsub_rn(p.x, q.x);
                    float dy = __fsub_rn(p.y, q.y);
                    float d2 = __fadd_rn(__fmul_rn(dx, dx), __fmul_rn(dy, dy));
                    if (d2 >= 25.0f) continue;
                    uint32_t j0 = sku0[j], j1 = sku1[j];
                    // u earlier iff (f2s, -idx) greater; j>i here so tie -> i
                    if (k0 && j0) {
                        int u = (k0 >= j0) ? i : j, v = i + j - u;
                        int pos = atomicAdd(&scount[0], 1);
                        if (pos < EBUFB) sbuf0[pos] = ((uint32_t)u << 12) | (uint32_t)v;
                    }
                    if (k1 && j1) {
                        int u = (k1 >= j1) ? i : j, v = i + j - u;
                        int pos = atomicAdd(&scount[1], 1);
                        if (pos < EBUFB) sbuf1[pos] = ((uint32_t)u << 12) | (uint32_t)v;
                    }
                }
            }
        }
    }
    __syncthreads();
    int c0 = min(scount[0], EBUFB), c1 = min(scount[1], EBUFB);
    for (int k = tid; k < c0; k += 256) edgesG[bid*EBUFB + k]        = sbuf0[k];
    for (int k = tid; k < c1; k += 256) edgesG[SECAP + bid*EBUFB + k] = sbuf1[k];
    if (tid == 0) { ecountG[bid] = (uint32_t)c0; ecountG[16 + bid] = (uint32_t)c1; }
}

// ---- K2: minimal serial core. Jacobi fixpoint on LDS bitsets + scatter ----
// keep[v] = valid[v] & !any(u->v edge with keep[u]); unique fixpoint on the
// key-ordered DAG == greedy NMS; converges in <= chain-depth rounds.
__global__ void __launch_bounds__(1024)
k_resolve(const float* __restrict__ sscG, const uint32_t* __restrict__ ranks,
          const uint32_t* __restrict__ edgesG, const uint32_t* __restrict__ ecountG,
          float* __restrict__ out)
{
    __shared__ float    ssc[N];             // 16 KB
    __shared__ uint16_t r16[N];             //  8 KB
    __shared__ uint32_t sedge[SECAP];       // 32 KB
    __shared__ uint32_t validw[128], keepw[128], suppw[128];
    __shared__ int schanged;
    const int cls = blockIdx.x, tid = threadIdx.x;

    for (int k = tid; k < N; k += 1024) {
        ssc[k] = sscG[cls*N + k];
        r16[k] = (uint16_t)ranks[cls*N + k];
    }
    int pref[16], cnts[16], total = 0;
    #pragma unroll
    for (int b = 0; b < 16; ++b) {
        pref[b] = total;
        int c = min((int)ecountG[cls*16 + b], EBUFB);
        cnts[b] = c; total += c;
    }
    const int ec = total;                  // <= SECAP by construction
    #pragma unroll
    for (int b = 0; b < 16; ++b)
        for (int k = tid; k < cnts[b]; k += 1024)
            sedge[pref[b] + k] = edgesG[cls*SECAP + b*EBUFB + k];
    __syncthreads();
    if (tid < 128) {
        uint32_t wb = 0;
        #pragma unroll
        for (int b = 0; b < 32; ++b)
            if (ssc[tid*32 + b] >= 0.05f) wb |= 1u << b;
        validw[tid] = wb; keepw[tid] = wb;
    }
    __syncthreads();

    for (int round = 0; round < N; ++round) {
        if (tid < 128) suppw[tid] = 0;
        if (tid == 0) schanged = 0;
        __syncthreads();
        for (int e = tid; e < ec; e += 1024) {
            uint32_t ed = sedge[e];
            int u = ed >> 12, v = ed & (N - 1);
            if ((keepw[u >> 5] >> (u & 31)) & 1u)
                atomicOr(&suppw[v >> 5], 1u << (v & 31));
        }
        __syncthreads();
        if (tid < 128) {
            uint32_t nw = validw[tid] & ~suppw[tid];
            if (nw != keepw[tid]) { keepw[tid] = nw; schanged = 1; }
        }
        __syncthreads();
        if (!schanged) break;
    }

    // output per SORTED slot (ranks form a permutation of 0..N-1)
    for (int k = tid; k < N; k += 1024) {
        int slot = r16[k];
        bool kp = (keepw[k >> 5] >> (k & 31)) & 1u;
        out[slot*5 + 3 + cls] = kp ? ssc[k] : 0.0f;
    }
}

extern "C" void kernel_launch(void* const* d_in, const int* in_sizes, int n_in,
                              void* d_out, int out_size, void* d_ws, size_t ws_size,
                              hipStream_t stream) {
    const float* logits = (const float*)d_in[0];  // [1,4096,3]
    const float* boxes  = (const float*)d_in[1];  // [1,4096,2]
    // d_in[2] = pred_gids, unused by the reference
    const float* tsz    = (const float*)d_in[3];  // [1,2]
    float* out = (float*)d_out;                   // [1,4096,5]

    uint8_t* ws = (uint8_t*)d_ws;
    float*    sscG    = (float*)   ws;              // 32 KB (2 classes)
    uint32_t* ranks   = (uint32_t*)(ws + 32768);    // 32 KB (2 classes)
    uint32_t* edgesG  = (uint32_t*)(ws + 65536);    // 64 KB (2 x SECAP)
    uint32_t* ecountG = (uint32_t*)(ws + 131072);   // 128 B (32 counts)

    hipLaunchKernelGGL(k_wide,    dim3(256), dim3(256),  0, stream,
                       logits, boxes, tsz, out, sscG, ranks, edgesG, ecountG);
    hipLaunchKernelGGL(k_resolve, dim3(2),   dim3(1024), 0, stream,
                       sscG, ranks, edgesG, ecountG, out);
}

// Round 11
// 86.074 us; speedup vs baseline: 2.3940x; 1.2392x over previous
//
#include <hip/hip_runtime.h>
#include <stdint.h>

#define N 4096
#define RG 32                 // 32x32 cells of 16 px over 512x512
#define BCAP 20               // bucket cap (measured max occupancy <= 20 at R9/R10)
#define NEB 8                 // edge blocks (512-pt chunks)
#define EBUFB 1024            // per-chunk per-class edge region (expect ~310)
#define SECAP 8192            // per-class edge cap (= NEB * EBUFB)

// monotonic float32 -> uint32 mapping (order-preserving)
__device__ __forceinline__ uint32_t f2s(float f) {
    uint32_t u = __float_as_uint(f);
    return (u & 0x80000000u) ? ~u : (u | 0x80000000u);
}

// ---- K1: wide, self-sufficient, disjoint roles by blockIdx:
//   0..127   : rank 64-point segment (keys recomputed from logits);
//              blocks 0 and 64 also stream per-class scores to ws
//   128..135 : out cols 0..2 for own 512-pt chunk + directed-edge build
//              (private LDS bins, private global edge region)
__global__ void __launch_bounds__(1024)
k_wide(const float* __restrict__ logits, const float* __restrict__ boxes,
       const float* __restrict__ tsz, float* __restrict__ out,
       float* __restrict__ sscG, uint32_t* __restrict__ ranks,
       uint32_t* __restrict__ edgesG, uint32_t* __restrict__ ecountG)
{
    __shared__ __align__(16) char smem[118784];
    __shared__ int scount[2];
    const int tid = threadIdx.x, bid = blockIdx.x;

    if (bid < 128) {
        // ---- rank role: 64 pts/block, 16 threads/pt x 256 compares ----
        const int cls = bid >> 6, seg = bid & 63;
        uint64_t* sk = (uint64_t*)smem;                        // 32 KB
        uint32_t (*part)[17] = (uint32_t(*)[17])(smem + 32768);
        const bool wssc = (bid == 0 || bid == 64);
        #pragma unroll
        for (int r = 0; r < 4; ++r) {
            int i = r * 1024 + tid;
            float x0 = logits[i*3+0], x1 = logits[i*3+1], x2 = logits[i*3+2];
            float mx = fmaxf(x0, fmaxf(x1, x2));
            float e0 = expf(x0 - mx), e1 = expf(x1 - mx), e2 = expf(x2 - mx);
            float s = (cls ? e1 : e0) / (e0 + e1 + e2);
            if (wssc) sscG[cls*N + i] = s;
            uint32_t kk = (s >= 0.05f) ? f2s(s) : 0u;   // invalid sorts last
            // tie-break: smaller original index first under DESCENDING sort
            sk[i] = ((uint64_t)kk << 32) | (uint32_t)(~(uint32_t)i);
        }
        __syncthreads();
        int pl = tid & 63, sub = tid >> 6;     // wave-uniform sub => broadcast reads
        uint64_t my = sk[seg*64 + pl];
        int cnt = 0, j0 = sub * (N/16);
        #pragma unroll 4
        for (int j = j0; j < j0 + N/16; j += 2) {
            ulong2 two = *(const ulong2*)&sk[j];   // 16B broadcast LDS read
            cnt += (two.x > my) ? 1 : 0;
            cnt += (two.y > my) ? 1 : 0;
        }
        part[pl][sub] = (uint32_t)cnt;
        __syncthreads();
        if (tid < 64) {
            uint32_t r = 0;
            #pragma unroll
            for (int s = 0; s < 16; ++s) r += part[tid][s];
            ranks[cls*N + seg*64 + tid] = r;
        }
        return;
    }

    // ---- edge role (blocks 128..135): chunk of 512 points ----
    const int chunk = bid - 128;
    float2*   spts  = (float2*)smem;                   // 32 KB @0
    uint32_t* sku0  = (uint32_t*)(smem + 32768);       // 16 KB
    uint32_t* sku1  = (uint32_t*)(smem + 49152);       // 16 KB
    uint32_t* cnt   = (uint32_t*)(smem + 65536);       //  4 KB
    uint16_t* bkt   = (uint16_t*)(smem + 69632);       // 40 KB
    uint32_t* sbuf0 = (uint32_t*)(smem + 110592);      //  4 KB
    uint32_t* sbuf1 = (uint32_t*)(smem + 114688);      //  4 KB

    for (int c = tid; c < RG*RG; c += 1024) cnt[c] = 0;
    if (tid < 2) scount[tid] = 0;
    __syncthreads();
    {
        const float w = tsz[0], h = tsz[1];
        #pragma unroll
        for (int r = 0; r < 4; ++r) {
            int k = r * 1024 + tid;
            float x0 = logits[k*3+0], x1 = logits[k*3+1], x2 = logits[k*3+2];
            float mx = fmaxf(x0, fmaxf(x1, x2));
            float e0 = expf(x0 - mx), e1 = expf(x1 - mx), e2 = expf(x2 - mx);
            float sum = e0 + e1 + e2;
            float s0 = e0 / sum, s1 = e1 / sum;
            float px = boxes[k*2+0] * w, py = boxes[k*2+1] * h;
            if ((k >> 9) == chunk) {           // own chunk: direct outputs
                out[k*5+0] = 1.0f - e2 / sum;  // tgt score
                out[k*5+1] = px;               // x (exact)
                out[k*5+2] = py;               // y (exact)
            }
            spts[k] = make_float2(px, py);
            sku0[k] = (s0 >= 0.05f) ? f2s(s0) : 0u;
            sku1[k] = (s1 >= 0.05f) ? f2s(s1) : 0u;
            int cx = min(max((int)(px * 0.0625f), 0), RG - 1);
            int cy = min(max((int)(py * 0.0625f), 0), RG - 1);
            uint32_t pos = atomicAdd(&cnt[cy*RG + cx], 1u);
            if (pos < BCAP) bkt[(cy*RG + cx)*BCAP + pos] = (uint16_t)k;
        }
    }
    __syncthreads();
    if (tid < 512) {
        int i = chunk * 512 + tid;             // 1 point/thread
        uint32_t k0 = sku0[i], k1 = sku1[i];
        if (k0 | k1) {
            float2 p = spts[i];
            int cx = min(max((int)(p.x * 0.0625f), 0), RG - 1);
            int cy = min(max((int)(p.y * 0.0625f), 0), RG - 1);
            // 2x2 window covers all <5px neighbors (5+5 < 16)
            float fx = p.x - 16.f * cx, fy = p.y - 16.f * cy;
            int xl = (fx < 5.f  && cx > 0     ) ? cx - 1 : cx;
            int xh = (fx > 11.f && cx < RG - 1) ? cx + 1 : cx;
            int yl = (fy < 5.f  && cy > 0     ) ? cy - 1 : cy;
            int yh = (fy > 11.f && cy < RG - 1) ? cy + 1 : cy;
            for (int yy = yl; yy <= yh; ++yy)
            for (int xx = xl; xx <= xh; ++xx) {
                int c = yy * RG + xx;
                int n = min((int)cnt[c], BCAP);
                for (int t = 0; t < n; ++t) {
                    int j = bkt[c*BCAP + t];
                    if (j <= i) continue;              // each unordered pair once
                    float2 q = spts[j];
                    float dx = __fsub_rn(p.x, q.x);
                    float dy = __fsub_rn(p.y, q.y);
                    float d2 = __fadd_rn(__fmul_rn(dx, dx), __fmul_rn(dy, dy));
                    if (d2 >= 25.0f) continue;
                    uint32_t j0 = sku0[j], j1 = sku1[j];
                    // u earlier iff (f2s, -idx) greater; j>i so tie -> i
                    if (k0 && j0) {
                        int u = (k0 >= j0) ? i : j, v = i + j - u;
                        int pos = atomicAdd(&scount[0], 1);
                        if (pos < EBUFB) sbuf0[pos] = ((uint32_t)u << 12) | (uint32_t)v;
                    }
                    if (k1 && j1) {
                        int u = (k1 >= j1) ? i : j, v = i + j - u;
                        int pos = atomicAdd(&scount[1], 1);
                        if (pos < EBUFB) sbuf1[pos] = ((uint32_t)u << 12) | (uint32_t)v;
                    }
                }
            }
        }
    }
    __syncthreads();
    int c0 = min(scount[0], EBUFB), c1 = min(scount[1], EBUFB);
    for (int k = tid; k < c0; k += 1024) edgesG[chunk*EBUFB + k]         = sbuf0[k];
    for (int k = tid; k < c1; k += 1024) edgesG[SECAP + chunk*EBUFB + k] = sbuf1[k];
    if (tid == 0) { ecountG[chunk] = (uint32_t)c0; ecountG[NEB + chunk] = (uint32_t)c1; }
}

// ---- K2: minimal serial core. Jacobi fixpoint on LDS bitsets + scatter ----
// keep[v] = valid[v] & !any(u->v edge with keep[u]); unique fixpoint on the
// key-ordered DAG == greedy NMS; converges in <= chain-depth rounds.
__global__ void __launch_bounds__(1024)
k_resolve(const float* __restrict__ sscG, const uint32_t* __restrict__ ranks,
          const uint32_t* __restrict__ edgesG, const uint32_t* __restrict__ ecountG,
          float* __restrict__ out)
{
    __shared__ float    ssc[N];             // 16 KB
    __shared__ uint16_t r16[N];             //  8 KB
    __shared__ uint32_t sedge[SECAP];       // 32 KB
    __shared__ uint32_t validw[128], keepw[128], suppw[128];
    __shared__ int schanged;
    const int cls = blockIdx.x, tid = threadIdx.x;

    for (int k = tid; k < N; k += 1024) {
        ssc[k] = sscG[cls*N + k];
        r16[k] = (uint16_t)ranks[cls*N + k];
    }
    int pref[NEB], cnts[NEB], total = 0;
    #pragma unroll
    for (int b = 0; b < NEB; ++b) {
        pref[b] = total;
        int c = min((int)ecountG[cls*NEB + b], EBUFB);
        cnts[b] = c; total += c;
    }
    const int ec = total;                  // <= SECAP by construction
    #pragma unroll
    for (int b = 0; b < NEB; ++b)
        for (int k = tid; k < cnts[b]; k += 1024)
            sedge[pref[b] + k] = edgesG[cls*SECAP + b*EBUFB + k];
    __syncthreads();
    if (tid < 128) {
        uint32_t wb = 0;
        #pragma unroll
        for (int b = 0; b < 32; ++b)
            if (ssc[tid*32 + b] >= 0.05f) wb |= 1u << b;
        validw[tid] = wb; keepw[tid] = wb;
    }
    __syncthreads();

    for (int round = 0; round < N; ++round) {
        if (tid < 128) suppw[tid] = 0;
        if (tid == 0) schanged = 0;
        __syncthreads();
        for (int e = tid; e < ec; e += 1024) {
            uint32_t ed = sedge[e];
            int u = ed >> 12, v = ed & (N - 1);
            if ((keepw[u >> 5] >> (u & 31)) & 1u)
                atomicOr(&suppw[v >> 5], 1u << (v & 31));
        }
        __syncthreads();
        if (tid < 128) {
            uint32_t nw = validw[tid] & ~suppw[tid];
            if (nw != keepw[tid]) { keepw[tid] = nw; schanged = 1; }
        }
        __syncthreads();
        if (!schanged) break;
    }

    // output per SORTED slot (ranks form a permutation of 0..N-1)
    for (int k = tid; k < N; k += 1024) {
        int slot = r16[k];
        bool kp = (keepw[k >> 5] >> (k & 31)) & 1u;
        out[slot*5 + 3 + cls] = kp ? ssc[k] : 0.0f;
    }
}

extern "C" void kernel_launch(void* const* d_in, const int* in_sizes, int n_in,
                              void* d_out, int out_size, void* d_ws, size_t ws_size,
                              hipStream_t stream) {
    const float* logits = (const float*)d_in[0];  // [1,4096,3]
    const float* boxes  = (const float*)d_in[1];  // [1,4096,2]
    // d_in[2] = pred_gids, unused by the reference
    const float* tsz    = (const float*)d_in[3];  // [1,2]
    float* out = (float*)d_out;                   // [1,4096,5]

    uint8_t* ws = (uint8_t*)d_ws;
    float*    sscG    = (float*)   ws;              // 32 KB (2 classes)
    uint32_t* ranks   = (uint32_t*)(ws + 32768);    // 32 KB (2 classes)
    uint32_t* edgesG  = (uint32_t*)(ws + 65536);    // 64 KB (2 x SECAP)
    uint32_t* ecountG = (uint32_t*)(ws + 131072);   // 64 B (16 counts)

    hipLaunchKernelGGL(k_wide,    dim3(136), dim3(1024), 0, stream,
                       logits, boxes, tsz, out, sscG, ranks, edgesG, ecountG);
    hipLaunchKernelGGL(k_resolve, dim3(2),   dim3(1024), 0, stream,
                       sscG, ranks, edgesG, ecountG, out);
}